// Round 7
// baseline (46.488 us; speedup 1.0000x reference)
//
#include <hip/hip_runtime.h>
#include <hip/hip_fp16.h>
#include <math.h>

// LightingProbes R7: 4 points/thread, register-resident vf4 I/O, zero barriers.
// Hypothesis: R1-R6 invariant ~35us is memory-latency exposure (1 point-stream
// per wave + block barriers). 4 unrolled point-pipelines/thread -> 4x ILP,
// 16 independent patch gathers in flight. Selection (10-cand separable),
// uv, f16 32B patches bit-identical to R6.

#define NPATCH 192000            // 6*16*16*125 patches

typedef float vf4 __attribute__((ext_vector_type(4)));
typedef unsigned int u32x4 __attribute__((ext_vector_type(4)));
typedef unsigned int u32x2 __attribute__((ext_vector_type(2)));

__device__ __forceinline__ float fastrcp(float x)  { return __builtin_amdgcn_rcpf(x); }
__device__ __forceinline__ float fastsqrt(float x) { return __builtin_amdgcn_sqrtf(x); }

__device__ __forceinline__ void up2(unsigned u, float& a, float& b) {
    __half2 h;
    *(unsigned*)&h = u;
    float2 f = __half22float2(h);
    a = f.x; b = f.y;
}

__device__ __forceinline__ void dimsort(float v,
    float& e0, float& e1, float& e2, int& c0, int& c1, int& c2)
{
    float f = (v + 3.0f) * (1.0f / 1.5f);
    int n = (int)floorf(f + 0.5f);
    n = n < 0 ? 0 : (n > 4 ? 4 : n);
    int s = n - 1;
    s = s < 0 ? 0 : (s > 2 ? 2 : s);

    float p0 = fmaf(1.5f, (float)s, -3.0f);
    float d0 = v - p0;
    float d1 = d0 - 1.5f;
    float d2 = d1 - 1.5f;
    float a0 = d0 * d0, a1 = d1 * d1, a2 = d2 * d2;
    int j0 = s, j1 = s + 1, j2 = s + 2;

    {   bool sw = a1 < a0;
        float ta = sw ? a1 : a0, tb = sw ? a0 : a1;
        int   ua = sw ? j1 : j0, ub = sw ? j0 : j1;
        a0 = ta; a1 = tb; j0 = ua; j1 = ub; }
    {   bool sw = a2 < a1;
        float ta = sw ? a2 : a1, tb = sw ? a1 : a2;
        int   ua = sw ? j2 : j1, ub = sw ? j1 : j2;
        a1 = ta; a2 = tb; j1 = ua; j2 = ub; }
    {   bool sw = a1 < a0;
        float ta = sw ? a1 : a0, tb = sw ? a0 : a1;
        int   ua = sw ? j1 : j0, ub = sw ? j0 : j1;
        a0 = ta; a1 = tb; j0 = ua; j1 = ub; }

    e0 = a0; e1 = a1; e2 = a2;
    c0 = j0; c1 = j1; c2 = j2;
}

#define INSERT(d, L, s0, s1, s2, s3, k0, k1, k2, k3)                          \
    {                                                                         \
        bool lt = (d) < s3; s3 = lt ? (d) : s3; k3 = lt ? (L) : k3;           \
        { bool cb = s3 < s2; float nd = cb ? s3 : s2, xd = cb ? s2 : s3;      \
          int ni = cb ? k3 : k2, xi = cb ? k2 : k3;                           \
          s2 = nd; s3 = xd; k2 = ni; k3 = xi; }                               \
        { bool cb = s2 < s1; float nd = cb ? s2 : s1, xd = cb ? s1 : s2;      \
          int ni = cb ? k2 : k1, xi = cb ? k1 : k2;                           \
          s1 = nd; s2 = xd; k1 = ni; k2 = xi; }                               \
        { bool cb = s1 < s0; float nd = cb ? s1 : s0, xd = cb ? s0 : s1;      \
          int ni = cb ? k1 : k0, xi = cb ? k0 : k1;                           \
          s0 = nd; s1 = xd; k0 = ni; k1 = xi; }                               \
    }

__device__ __forceinline__ void uv_setup(
    float dx, float dy, float dz,
    int& face, int& t00,
    float& w00, float& w01, float& w10, float& w11)
{
    float nrm = sqrtf(fmaf(dx, dx, fmaf(dy, dy, dz * dz)));
    nrm = fmaxf(nrm, 1e-12f);
    float inv = fastrcp(nrm);
    float ux = dx * inv, uy = dy * inv, uz = dz * inv;
    float ax = fabsf(ux), ay = fabsf(uy), az = fabsf(uz);

    bool xd = (ax >= ay) && (ax >= az);
    float den, un, vn;
    if (xd) {
        face = (ux > 0.0f) ? 0 : 1;
        den = ax; un = (ux > 0.0f) ? -uz : uz; vn = -uy;
    } else if (ay >= az) {
        face = (uy > 0.0f) ? 2 : 3;
        den = ay; un = ux; vn = (uy > 0.0f) ? uz : -uz;
    } else {
        face = (uz > 0.0f) ? 4 : 5;
        den = az; un = (uz > 0.0f) ? ux : -ux; vn = -uy;
    }
    float rden = fastrcp(den + 1e-8f);
    float u = un * rden;
    float v = vn * rden;
    u = fminf(1.0f, fmaxf(-1.0f, u));
    v = fminf(1.0f, fmaxf(-1.0f, v));

    float fx = (u + 1.0f) * 0.5f * 15.0f;
    float fy = (v + 1.0f) * 0.5f * 15.0f;
    float x0f = floorf(fx), y0f = floorf(fy);
    float wx = fx - x0f, wy = fy - y0f;
    int px0 = (int)x0f; px0 = px0 < 0 ? 0 : (px0 > 15 ? 15 : px0);
    int py0 = (int)y0f; py0 = py0 < 0 ? 0 : (py0 > 15 ? 15 : py0);

    w00 = (1.0f - wx) * (1.0f - wy);
    w01 = wx * (1.0f - wy);
    w10 = (1.0f - wx) * wy;
    w11 = wx * wy;

    t00 = py0 * 16 + px0;
}

// full per-point pipeline up to patch addresses + weights
__device__ __forceinline__ void point_setup(
    float x, float y, float z, float dx, float dy, float dz,
    int& pi0, int& pi1, int& pi2, int& pi3,
    float& w0, float& w1, float& w2, float& w3,
    float& w00, float& w01, float& w10, float& w11)
{
    float ex0, ex1, ex2, ey0, ey1, ey2, ez0, ez1, ez2;
    int jx0, jx1, jx2, jy0, jy1, jy2, jz0, jz1, jz2;
    dimsort(x, ex0, ex1, ex2, jx0, jx1, jx2);
    dimsort(y, ey0, ey1, ey2, jy0, jy1, jy2);
    dimsort(z, ez0, ez1, ez2, jz0, jz1, jz2);

    int X0 = jx0 * 25, X1 = jx1 * 25, X2 = jx2 * 25;
    int Y0 = jy0 * 5,  Y1 = jy1 * 5,  Y2 = jy2 * 5;
    int Z0 = jz0,      Z1 = jz1,      Z2 = jz2;

    float exy00 = ex0 + ey0, exy10 = ex1 + ey0, exy01 = ex0 + ey1;
    float exy11 = ex1 + ey1, exy20 = ex2 + ey0, exy02 = ex0 + ey2;
    int   kxy00 = X0 + Y0,   kxy10 = X1 + Y0,   kxy01 = X0 + Y1;
    int   kxy11 = X1 + Y1,   kxy20 = X2 + Y0,   kxy02 = X0 + Y2;

    float s0 = exy00 + ez0, s1 = 1e30f, s2 = 1e30f, s3 = 1e30f;
    int   k0 = kxy00 + Z0,  k1 = 0,     k2 = 0,     k3 = 0;

    { float d = exy10 + ez0; int L = kxy10 + Z0; INSERT(d, L, s0, s1, s2, s3, k0, k1, k2, k3); }
    { float d = exy01 + ez0; int L = kxy01 + Z0; INSERT(d, L, s0, s1, s2, s3, k0, k1, k2, k3); }
    { float d = exy00 + ez1; int L = kxy00 + Z1; INSERT(d, L, s0, s1, s2, s3, k0, k1, k2, k3); }
    { float d = exy11 + ez0; int L = kxy11 + Z0; INSERT(d, L, s0, s1, s2, s3, k0, k1, k2, k3); }
    { float d = exy10 + ez1; int L = kxy10 + Z1; INSERT(d, L, s0, s1, s2, s3, k0, k1, k2, k3); }
    { float d = exy01 + ez1; int L = kxy01 + Z1; INSERT(d, L, s0, s1, s2, s3, k0, k1, k2, k3); }
    { float d = exy20 + ez0; int L = kxy20 + Z0; INSERT(d, L, s0, s1, s2, s3, k0, k1, k2, k3); }
    { float d = exy02 + ez0; int L = kxy02 + Z0; INSERT(d, L, s0, s1, s2, s3, k0, k1, k2, k3); }
    { float d = exy00 + ez2; int L = kxy00 + Z2; INSERT(d, L, s0, s1, s2, s3, k0, k1, k2, k3); }

    w0 = fastrcp(fastsqrt(s0) + 1e-4f);
    w1 = fastrcp(fastsqrt(s1) + 1e-4f);
    w2 = fastrcp(fastsqrt(s2) + 1e-4f);
    w3 = fastrcp(fastsqrt(s3) + 1e-4f);
    float wi = fastrcp(w0 + w1 + w2 + w3);
    w0 *= wi; w1 *= wi; w2 *= wi; w3 *= wi;

    int face, t00;
    uv_setup(dx, dy, dz, face, t00, w00, w01, w10, w11);

    int cell = (face * 256 + t00) * 125;
    pi0 = cell + k0; pi1 = cell + k1; pi2 = cell + k2; pi3 = cell + k3;
}

// gather one patch + accumulate
__device__ __forceinline__ void patch_accum(
    const unsigned int* __restrict__ patches, int pidx, float wn,
    float w00, float w01, float w10, float w11,
    float& r, float& g, float& b)
{
    const unsigned* pp = patches + (size_t)pidx * 8;
    u32x4 lo = *(const u32x4*)pp;
    u32x2 hi = *(const u32x2*)(pp + 4);
    float r00, g00, b00, r01, g01, b01, r10, g10, b10, r11, g11, b11;
    up2(lo.x, r00, g00);
    up2(lo.y, b00, r01);
    up2(lo.z, g01, b01);
    up2(lo.w, r10, g10);
    up2(hi.x, b10, r11);
    up2(hi.y, g11, b11);
    float rr = fmaf(r00, w00, fmaf(r01, w01, fmaf(r10, w10, r11 * w11)));
    float gg = fmaf(g00, w00, fmaf(g01, w01, fmaf(g10, w10, g11 * w11)));
    float bv = fmaf(b00, w00, fmaf(b01, w01, fmaf(b10, w10, b11 * w11)));
    r = fmaf(wn, rr, r);
    g = fmaf(wn, gg, g);
    b = fmaf(wn, bv, b);
}

// ---- build f16 patches (identical to R6) ----
__global__ __launch_bounds__(256) void build_patches_f16(
    const float* __restrict__ cube, unsigned int* __restrict__ patches)
{
    int t = blockIdx.x * blockDim.x + threadIdx.x;
    if (t >= NPATCH) return;
    int p   = t % 125;
    int q   = t / 125;
    int px0 = q % 16; q /= 16;
    int py0 = q % 16;
    int face = q / 16;
    int px1 = px0 + 1 > 15 ? 15 : px0 + 1;
    int py1 = py0 + 1 > 15 ? 15 : py0 + 1;

    const float* f = cube + (p * 6 + face) * 768;
    int o00 = (py0 * 16 + px0) * 3;
    int o01 = (py0 * 16 + px1) * 3;
    int o10 = (py1 * 16 + px0) * 3;
    int o11 = (py1 * 16 + px1) * 3;

    float v[12];
    v[0] = f[o00]; v[1]  = f[o00 + 1]; v[2]  = f[o00 + 2];
    v[3] = f[o01]; v[4]  = f[o01 + 1]; v[5]  = f[o01 + 2];
    v[6] = f[o10]; v[7]  = f[o10 + 1]; v[8]  = f[o10 + 2];
    v[9] = f[o11]; v[10] = f[o11 + 1]; v[11] = f[o11 + 2];

    unsigned u[8];
#pragma unroll
    for (int j = 0; j < 6; j++) {
        __half a = __float2half(v[2 * j]);
        __half b = __float2half(v[2 * j + 1]);
        u[j] = (unsigned)__half_as_ushort(a) | ((unsigned)__half_as_ushort(b) << 16);
    }
    u[6] = 0; u[7] = 0;

    u32x4* dst = (u32x4*)(patches + (size_t)t * 8);
    u32x4 a = {u[0], u[1], u[2], u[3]};
    u32x4 b = {u[4], u[5], u[6], u[7]};
    dst[0] = a;
    dst[1] = b;
}

// ---- main: 4 points per thread, register vf4 I/O, no barriers ----
__global__ __launch_bounds__(128) void lp_f16_q(
    const float* __restrict__ xyz,
    const float* __restrict__ vdirs,
    const unsigned int* __restrict__ patches,
    float* __restrict__ out,
    int N)
{
    int t = blockIdx.x * blockDim.x + threadIdx.x;
    int p0 = t * 4;
    if (p0 >= N) return;
    bool full = (p0 + 3) < N;

    float X[4], Y[4], Z[4], DX[4], DY[4], DZ[4];

    if (full) {
        const vf4* x4 = (const vf4*)(xyz + p0 * 3);
        const vf4* d4 = (const vf4*)(vdirs + p0 * 3);
        vf4 a = __builtin_nontemporal_load(&x4[0]);
        vf4 b = __builtin_nontemporal_load(&x4[1]);
        vf4 c = __builtin_nontemporal_load(&x4[2]);
        X[0] = a.x; Y[0] = a.y; Z[0] = a.z;
        X[1] = a.w; Y[1] = b.x; Z[1] = b.y;
        X[2] = b.z; Y[2] = b.w; Z[2] = c.x;
        X[3] = c.y; Y[3] = c.z; Z[3] = c.w;
        vf4 e = __builtin_nontemporal_load(&d4[0]);
        vf4 f = __builtin_nontemporal_load(&d4[1]);
        vf4 g = __builtin_nontemporal_load(&d4[2]);
        DX[0] = e.x; DY[0] = e.y; DZ[0] = e.z;
        DX[1] = e.w; DY[1] = f.x; DZ[1] = f.y;
        DX[2] = f.z; DY[2] = f.w; DZ[2] = g.x;
        DX[3] = g.y; DY[3] = g.z; DZ[3] = g.w;
    } else {
#pragma unroll
        for (int j = 0; j < 4; j++) {
            int i = p0 + j < N ? p0 + j : N - 1;
            X[j]  = xyz[3 * i];  Y[j]  = xyz[3 * i + 1];  Z[j]  = xyz[3 * i + 2];
            DX[j] = vdirs[3 * i]; DY[j] = vdirs[3 * i + 1]; DZ[j] = vdirs[3 * i + 2];
        }
    }

    // phase 1: all 4 points' setup (independent chains -> ILP)
    int pi0[4], pi1[4], pi2[4], pi3[4];
    float w0[4], w1[4], w2[4], w3[4];
    float w00[4], w01[4], w10[4], w11[4];
#pragma unroll
    for (int j = 0; j < 4; j++) {
        point_setup(X[j], Y[j], Z[j], DX[j], DY[j], DZ[j],
                    pi0[j], pi1[j], pi2[j], pi3[j],
                    w0[j], w1[j], w2[j], w3[j],
                    w00[j], w01[j], w10[j], w11[j]);
    }

    // phase 2: 16 independent gathers + accumulate
    float R[4], G[4], B[4];
#pragma unroll
    for (int j = 0; j < 4; j++) {
        R[j] = 0.0f; G[j] = 0.0f; B[j] = 0.0f;
        patch_accum(patches, pi0[j], w0[j], w00[j], w01[j], w10[j], w11[j], R[j], G[j], B[j]);
        patch_accum(patches, pi1[j], w1[j], w00[j], w01[j], w10[j], w11[j], R[j], G[j], B[j]);
        patch_accum(patches, pi2[j], w2[j], w00[j], w01[j], w10[j], w11[j], R[j], G[j], B[j]);
        patch_accum(patches, pi3[j], w3[j], w00[j], w01[j], w10[j], w11[j], R[j], G[j], B[j]);
    }

    if (full) {
        vf4* o4 = (vf4*)(out + p0 * 3);
        vf4 a = {R[0], G[0], B[0], R[1]};
        vf4 b = {G[1], B[1], R[2], G[2]};
        vf4 c = {B[2], R[3], G[3], B[3]};
        __builtin_nontemporal_store(a, &o4[0]);
        __builtin_nontemporal_store(b, &o4[1]);
        __builtin_nontemporal_store(c, &o4[2]);
    } else {
#pragma unroll
        for (int j = 0; j < 4; j++) {
            if (p0 + j < N) {
                out[3 * (p0 + j)]     = R[j];
                out[3 * (p0 + j) + 1] = G[j];
                out[3 * (p0 + j) + 2] = B[j];
            }
        }
    }
}

extern "C" void kernel_launch(void* const* d_in, const int* in_sizes, int n_in,
                              void* d_out, int out_size, void* d_ws, size_t ws_size,
                              hipStream_t stream) {
    const float* xyz  = (const float*)d_in[0];
    const float* vd   = (const float*)d_in[1];
    const float* cube = (const float*)d_in[2];
    float* outp = (float*)d_out;
    int N = in_sizes[0] / 3;
    int nthreads = (N + 3) / 4;
    int blocks = (nthreads + 127) / 128;

    unsigned int* patches = (unsigned int*)d_ws;
    hipLaunchKernelGGL(build_patches_f16, dim3((NPATCH + 255) / 256), dim3(256), 0, stream,
                       cube, patches);
    hipLaunchKernelGGL(lp_f16_q, dim3(blocks), dim3(128), 0, stream,
                       xyz, vd, patches, outp, N);
}

// Round 8
// 34.397 us; speedup vs baseline: 1.3515x; 1.3515x over previous
//
#include <hip/hip_runtime.h>
#include <math.h>

// LightingProbes R8: R6 structure (1pt/thread, 256-block, LDS-staged I/O,
// 10-candidate separable selection) + 16B shared-exp patches:
// 12 signed 10-bit mantissas + 6-bit patch exponent in one u32x4.
// -> 4 gather instrs/pt (was 8), 3.07MB table (L2-resident per XCD).

#define NPATCH 192000            // 6*16*16*125 patches

typedef float vf4 __attribute__((ext_vector_type(4)));
typedef unsigned int u32x4 __attribute__((ext_vector_type(4)));

__device__ __forceinline__ float fastrcp(float x)  { return __builtin_amdgcn_rcpf(x); }
__device__ __forceinline__ float fastsqrt(float x) { return __builtin_amdgcn_sqrtf(x); }

__device__ __forceinline__ void dimsort(float v,
    float& e0, float& e1, float& e2, int& c0, int& c1, int& c2)
{
    float f = (v + 3.0f) * (1.0f / 1.5f);
    int n = (int)floorf(f + 0.5f);
    n = n < 0 ? 0 : (n > 4 ? 4 : n);
    int s = n - 1;
    s = s < 0 ? 0 : (s > 2 ? 2 : s);

    float p0 = fmaf(1.5f, (float)s, -3.0f);
    float d0 = v - p0;
    float d1 = d0 - 1.5f;
    float d2 = d1 - 1.5f;
    float a0 = d0 * d0, a1 = d1 * d1, a2 = d2 * d2;
    int j0 = s, j1 = s + 1, j2 = s + 2;

    {   bool sw = a1 < a0;
        float ta = sw ? a1 : a0, tb = sw ? a0 : a1;
        int   ua = sw ? j1 : j0, ub = sw ? j0 : j1;
        a0 = ta; a1 = tb; j0 = ua; j1 = ub; }
    {   bool sw = a2 < a1;
        float ta = sw ? a2 : a1, tb = sw ? a1 : a2;
        int   ua = sw ? j2 : j1, ub = sw ? j1 : j2;
        a1 = ta; a2 = tb; j1 = ua; j2 = ub; }
    {   bool sw = a1 < a0;
        float ta = sw ? a1 : a0, tb = sw ? a0 : a1;
        int   ua = sw ? j1 : j0, ub = sw ? j0 : j1;
        a0 = ta; a1 = tb; j0 = ua; j1 = ub; }

    e0 = a0; e1 = a1; e2 = a2;
    c0 = j0; c1 = j1; c2 = j2;
}

#define INSERT(d, L, s0, s1, s2, s3, k0, k1, k2, k3)                          \
    {                                                                         \
        bool lt = (d) < s3; s3 = lt ? (d) : s3; k3 = lt ? (L) : k3;           \
        { bool cb = s3 < s2; float nd = cb ? s3 : s2, xd = cb ? s2 : s3;      \
          int ni = cb ? k3 : k2, xi = cb ? k2 : k3;                           \
          s2 = nd; s3 = xd; k2 = ni; k3 = xi; }                               \
        { bool cb = s2 < s1; float nd = cb ? s2 : s1, xd = cb ? s1 : s2;      \
          int ni = cb ? k2 : k1, xi = cb ? k1 : k2;                           \
          s1 = nd; s2 = xd; k1 = ni; k2 = xi; }                               \
        { bool cb = s1 < s0; float nd = cb ? s1 : s0, xd = cb ? s0 : s1;      \
          int ni = cb ? k1 : k0, xi = cb ? k0 : k1;                           \
          s0 = nd; s1 = xd; k0 = ni; k1 = xi; }                               \
    }

__device__ __forceinline__ void uv_setup(
    float dx, float dy, float dz,
    int& face, int& t00,
    float& w00, float& w01, float& w10, float& w11)
{
    float nrm = sqrtf(fmaf(dx, dx, fmaf(dy, dy, dz * dz)));
    nrm = fmaxf(nrm, 1e-12f);
    float inv = fastrcp(nrm);
    float ux = dx * inv, uy = dy * inv, uz = dz * inv;
    float ax = fabsf(ux), ay = fabsf(uy), az = fabsf(uz);

    bool xd = (ax >= ay) && (ax >= az);
    float den, un, vn;
    if (xd) {
        face = (ux > 0.0f) ? 0 : 1;
        den = ax; un = (ux > 0.0f) ? -uz : uz; vn = -uy;
    } else if (ay >= az) {
        face = (uy > 0.0f) ? 2 : 3;
        den = ay; un = ux; vn = (uy > 0.0f) ? uz : -uz;
    } else {
        face = (uz > 0.0f) ? 4 : 5;
        den = az; un = (uz > 0.0f) ? ux : -ux; vn = -uy;
    }
    float rden = fastrcp(den + 1e-8f);
    float u = un * rden;
    float v = vn * rden;
    u = fminf(1.0f, fmaxf(-1.0f, u));
    v = fminf(1.0f, fmaxf(-1.0f, v));

    float fx = (u + 1.0f) * 0.5f * 15.0f;
    float fy = (v + 1.0f) * 0.5f * 15.0f;
    float x0f = floorf(fx), y0f = floorf(fy);
    float wx = fx - x0f, wy = fy - y0f;
    int px0 = (int)x0f; px0 = px0 < 0 ? 0 : (px0 > 15 ? 15 : px0);
    int py0 = (int)y0f; py0 = py0 < 0 ? 0 : (py0 > 15 ? 15 : py0);

    w00 = (1.0f - wx) * (1.0f - wy);
    w01 = wx * (1.0f - wy);
    w10 = (1.0f - wx) * wy;
    w11 = wx * wy;

    t00 = py0 * 16 + px0;
}

// ---- build 16B shared-exp patches ----
// word j (j=0..3): 3 mantissas (10-bit signed, bits 0..29).
// exponent E (6 bits): w0[31:30]=E[1:0], w1[31:30]=E[3:2], w2[31:30]=E[5:4].
// value = m * 2^(E-40), mantissa = rint(v * 2^(40-E)) clamped to [-511,511].
__global__ __launch_bounds__(256) void build_patches_se(
    const float* __restrict__ cube, u32x4* __restrict__ patches)
{
    int t = blockIdx.x * blockDim.x + threadIdx.x;
    if (t >= NPATCH) return;
    int p   = t % 125;
    int q   = t / 125;
    int px0 = q % 16; q /= 16;
    int py0 = q % 16;
    int face = q / 16;
    int px1 = px0 + 1 > 15 ? 15 : px0 + 1;
    int py1 = py0 + 1 > 15 ? 15 : py0 + 1;

    const float* f = cube + (p * 6 + face) * 768;
    int o00 = (py0 * 16 + px0) * 3;
    int o01 = (py0 * 16 + px1) * 3;
    int o10 = (py1 * 16 + px0) * 3;
    int o11 = (py1 * 16 + px1) * 3;

    float v[12];
    v[0] = f[o00]; v[1]  = f[o00 + 1]; v[2]  = f[o00 + 2];
    v[3] = f[o01]; v[4]  = f[o01 + 1]; v[5]  = f[o01 + 2];
    v[6] = f[o10]; v[7]  = f[o10 + 1]; v[8]  = f[o10 + 2];
    v[9] = f[o11]; v[10] = f[o11 + 1]; v[11] = f[o11 + 2];

    float mx = 0.0f;
#pragma unroll
    for (int j = 0; j < 12; j++) mx = fmaxf(mx, fabsf(v[j]));

    int E;
    if (mx == 0.0f) {
        E = 0;
    } else {
        unsigned mb = __float_as_uint(mx);
        int eb = (int)((mb >> 23) & 0xFF) - 127;   // floor(log2(mx))
        E = eb + 32;                                // 2^(E-31) >= mx
        E = E < 0 ? 0 : (E > 63 ? 63 : E);
    }
    float mscale = __uint_as_float((unsigned)(167 - E) << 23);   // 2^(40-E)

    unsigned m[12];
#pragma unroll
    for (int j = 0; j < 12; j++) {
        float s = rintf(v[j] * mscale);
        s = fminf(511.0f, fmaxf(-511.0f, s));
        m[j] = (unsigned)((int)s) & 0x3FF;
    }

    unsigned w0 = m[0] | (m[1] << 10) | (m[2] << 20) | (((unsigned)E & 3) << 30);
    unsigned w1 = m[3] | (m[4] << 10) | (m[5] << 20) | ((((unsigned)E >> 2) & 3) << 30);
    unsigned w2 = m[6] | (m[7] << 10) | (m[8] << 20) | ((((unsigned)E >> 4) & 3) << 30);
    unsigned w3 = m[9] | (m[10] << 10) | (m[11] << 20);

    u32x4 o = {w0, w1, w2, w3};
    patches[t] = o;
}

__device__ __forceinline__ float dec(unsigned w, int sh) {
    // mantissa at bits [sh+9 : sh], signed
    return (float)(((int)(w << (22 - sh))) >> 22);
}

__global__ __launch_bounds__(256) void lp_se(
    const float* __restrict__ xyz,
    const float* __restrict__ vdirs,
    const u32x4* __restrict__ patches,
    float* __restrict__ out,
    int N)
{
    __shared__ float sh[1536];

    int tid = threadIdx.x;
    int b0  = blockIdx.x * 256;
    int nPts = N - b0; nPts = nPts > 256 ? 256 : nPts;
    int nflt = nPts * 3;
    int base4 = (b0 * 3) >> 2;

    const vf4* x4 = (const vf4*)xyz;
    const vf4* d4 = (const vf4*)vdirs;
    if (tid * 4 < nflt) {
        vf4 vx = __builtin_nontemporal_load(&x4[base4 + tid]);
        ((vf4*)sh)[tid] = vx;
        vf4 vd = __builtin_nontemporal_load(&d4[base4 + tid]);
        ((vf4*)(sh + 768))[tid] = vd;
    }
    __syncthreads();

    float r = 0.0f, g = 0.0f, b = 0.0f;
    if (tid < nPts) {
        float x  = sh[3 * tid + 0];
        float y  = sh[3 * tid + 1];
        float z  = sh[3 * tid + 2];
        float dx = sh[768 + 3 * tid + 0];
        float dy = sh[768 + 3 * tid + 1];
        float dz = sh[768 + 3 * tid + 2];

        // ---- 10-candidate separable top-4 selection (identical to R6) ----
        float ex0, ex1, ex2, ey0, ey1, ey2, ez0, ez1, ez2;
        int jx0, jx1, jx2, jy0, jy1, jy2, jz0, jz1, jz2;
        dimsort(x, ex0, ex1, ex2, jx0, jx1, jx2);
        dimsort(y, ey0, ey1, ey2, jy0, jy1, jy2);
        dimsort(z, ez0, ez1, ez2, jz0, jz1, jz2);

        int X0 = jx0 * 25, X1 = jx1 * 25, X2 = jx2 * 25;
        int Y0 = jy0 * 5,  Y1 = jy1 * 5,  Y2 = jy2 * 5;
        int Z0 = jz0,      Z1 = jz1,      Z2 = jz2;

        float exy00 = ex0 + ey0, exy10 = ex1 + ey0, exy01 = ex0 + ey1;
        float exy11 = ex1 + ey1, exy20 = ex2 + ey0, exy02 = ex0 + ey2;
        int   kxy00 = X0 + Y0,   kxy10 = X1 + Y0,   kxy01 = X0 + Y1;
        int   kxy11 = X1 + Y1,   kxy20 = X2 + Y0,   kxy02 = X0 + Y2;

        float s0 = exy00 + ez0, s1 = 1e30f, s2 = 1e30f, s3 = 1e30f;
        int   k0 = kxy00 + Z0,  k1 = 0,     k2 = 0,     k3 = 0;

        { float d = exy10 + ez0; int L = kxy10 + Z0; INSERT(d, L, s0, s1, s2, s3, k0, k1, k2, k3); }
        { float d = exy01 + ez0; int L = kxy01 + Z0; INSERT(d, L, s0, s1, s2, s3, k0, k1, k2, k3); }
        { float d = exy00 + ez1; int L = kxy00 + Z1; INSERT(d, L, s0, s1, s2, s3, k0, k1, k2, k3); }
        { float d = exy11 + ez0; int L = kxy11 + Z0; INSERT(d, L, s0, s1, s2, s3, k0, k1, k2, k3); }
        { float d = exy10 + ez1; int L = kxy10 + Z1; INSERT(d, L, s0, s1, s2, s3, k0, k1, k2, k3); }
        { float d = exy01 + ez1; int L = kxy01 + Z1; INSERT(d, L, s0, s1, s2, s3, k0, k1, k2, k3); }
        { float d = exy20 + ez0; int L = kxy20 + Z0; INSERT(d, L, s0, s1, s2, s3, k0, k1, k2, k3); }
        { float d = exy02 + ez0; int L = kxy02 + Z0; INSERT(d, L, s0, s1, s2, s3, k0, k1, k2, k3); }
        { float d = exy00 + ez2; int L = kxy00 + Z2; INSERT(d, L, s0, s1, s2, s3, k0, k1, k2, k3); }

        float w0 = fastrcp(fastsqrt(s0) + 1e-4f);
        float w1 = fastrcp(fastsqrt(s1) + 1e-4f);
        float w2 = fastrcp(fastsqrt(s2) + 1e-4f);
        float w3 = fastrcp(fastsqrt(s3) + 1e-4f);
        float wi = fastrcp(w0 + w1 + w2 + w3);
        w0 *= wi; w1 *= wi; w2 *= wi; w3 *= wi;

        int face, t00;
        float w00, w01, w10, w11;
        uv_setup(dx, dy, dz, face, t00, w00, w01, w10, w11);

        int cell = (face * 256 + t00) * 125;

        // ---- 4 gathers (1 dwordx4 each) + shared-exp decode + accumulate ----
#pragma unroll
        for (int k = 0; k < 4; k++) {
            int   p  = (k == 0) ? k0 : (k == 1) ? k1 : (k == 2) ? k2 : k3;
            float wn = (k == 0) ? w0 : (k == 1) ? w1 : (k == 2) ? w2 : w3;
            u32x4 pw = patches[cell + p];

            int E = (int)((pw.x >> 30) | (((pw.y >> 30) & 3u) << 2) | (((pw.z >> 30) & 3u) << 4));
            float s = __uint_as_float((unsigned)(E + 87) << 23);   // 2^(E-40)
            float wns = wn * s;

            float r00 = dec(pw.x, 0),  g00 = dec(pw.x, 10), b00 = dec(pw.x, 20);
            float r01 = dec(pw.y, 0),  g01 = dec(pw.y, 10), b01 = dec(pw.y, 20);
            float r10 = dec(pw.z, 0),  g10 = dec(pw.z, 10), b10 = dec(pw.z, 20);
            float r11 = dec(pw.w, 0),  g11 = dec(pw.w, 10), b11 = dec(pw.w, 20);

            float rr = fmaf(r00, w00, fmaf(r01, w01, fmaf(r10, w10, r11 * w11)));
            float gg = fmaf(g00, w00, fmaf(g01, w01, fmaf(g10, w10, g11 * w11)));
            float bv = fmaf(b00, w00, fmaf(b01, w01, fmaf(b10, w10, b11 * w11)));
            r = fmaf(wns, rr, r);
            g = fmaf(wns, gg, g);
            b = fmaf(wns, bv, b);
        }
    }

    __syncthreads();
    if (tid < nPts) {
        sh[3 * tid + 0] = r;
        sh[3 * tid + 1] = g;
        sh[3 * tid + 2] = b;
    }
    __syncthreads();
    if (tid * 4 < nflt) {
        vf4* o4 = (vf4*)out;
        __builtin_nontemporal_store(((vf4*)sh)[tid], &o4[base4 + tid]);
    }
}

extern "C" void kernel_launch(void* const* d_in, const int* in_sizes, int n_in,
                              void* d_out, int out_size, void* d_ws, size_t ws_size,
                              hipStream_t stream) {
    const float* xyz  = (const float*)d_in[0];
    const float* vd   = (const float*)d_in[1];
    const float* cube = (const float*)d_in[2];
    float* outp = (float*)d_out;
    int N = in_sizes[0] / 3;
    int blocks = (N + 255) / 256;

    u32x4* patches = (u32x4*)d_ws;    // 3.07 MB
    hipLaunchKernelGGL(build_patches_se, dim3((NPATCH + 255) / 256), dim3(256), 0, stream,
                       cube, patches);
    hipLaunchKernelGGL(lp_se, dim3(blocks), dim3(256), 0, stream,
                       xyz, vd, patches, outp, N);
}